// Round 4
// baseline (409.038 us; speedup 1.0000x reference)
//
#include <hip/hip_runtime.h>
#include <hip/hip_bf16.h>
#include <stdint.h>

// Problem constants
#define BB 4
#define TT 24
#define NN 325          // sequence length per (b,t)
#define DD 512
#define NH 8
#define DKH 64          // d_k per head
#define MROWS (BB*TT*NN)   // 31200 total rows
#define BTC (BB*TT)        // 96

typedef __attribute__((ext_vector_type(4))) float f32x4;
typedef __attribute__((ext_vector_type(8))) short s16x8;
typedef __attribute__((ext_vector_type(4))) unsigned int u32x4;
typedef __attribute__((ext_vector_type(2))) unsigned int u32x2;

__device__ __forceinline__ unsigned short f2bf(float f) {
    union { float f; unsigned int u; } x; x.f = f;
    unsigned int u = x.u;
    u += 0x7fffu + ((u >> 16) & 1u);   // RNE
    return (unsigned short)(u >> 16);
}
// packed f32->bf16 (RNE) via HW instruction
__device__ __forceinline__ unsigned int cvt2(float a, float b) {
    unsigned int r;
    asm("v_cvt_pk_bf16_f32 %0, %1, %2" : "=v"(r) : "v"(a), "v"(b));
    return r;
}

__device__ __forceinline__ void gload16(const void* g, void* l) {
    __builtin_amdgcn_global_load_lds((const __attribute__((address_space(1))) void*)g,
                                     (__attribute__((address_space(3))) void*)l, 16, 0, 0);
}

// ---------------------------------------------------------------------------
// K0: weight prep. Permute head-interleaved columns (d = dk*8+h  ->  h*64+dk),
// transpose to [n][k] layout, convert to bf16.
// ---------------------------------------------------------------------------
__global__ void prep_kernel(const float* __restrict__ Wh, const float* __restrict__ bias,
                            const float* __restrict__ Wo,
                            unsigned short* __restrict__ WtH, unsigned short* __restrict__ WtO,
                            float* __restrict__ biasp)
{
    int idx = blockIdx.x * 256 + threadIdx.x;
    if (idx < 3*512*512) {
        int i = idx >> 18; int rem = idx & 262143;
        int cp = rem >> 9; int e = rem & 511;
        int c = ((cp & 63) << 3) | (cp >> 6);
        WtH[idx] = f2bf(Wh[(i << 18) + (e << 9) + c]);
        return;
    }
    int idx2 = idx - 3*512*512;
    if (idx2 >= 0 && idx2 < 512*512) {
        int c = idx2 >> 9; int ep = idx2 & 511;
        int row = ((ep & 63) << 3) | (ep >> 6);
        WtO[idx2] = f2bf(Wo[(row << 9) + c]);
        return;
    }
    int idx3 = idx2 - 512*512;
    if (idx3 >= 0 && idx3 < 3*512) {
        int i = idx3 >> 9; int cp = idx3 & 511;
        int c = ((cp & 63) << 3) | (cp >> 6);
        biasp[idx3] = bias[(i << 9) + c];
    }
}

// ---------------------------------------------------------------------------
// K1: QKV projection GEMM, double-buffered counted-prefetch pipeline.
// A fp32 reg-staged (coalesced f32x4 loads -> cvt_pk_bf16 -> swizzled LDS
// writes), B bf16 via global_load_lds (pre-swizzled source). Loads for tile
// k+1 issue BEFORE the MFMA cluster of tile k; one barrier per K-step whose
// drain is cheap (loads are old). BM=128 BN=128 BK=64, 4 waves (2x2),
// LDS 64 KB -> 2 blocks/CU. XCD-chunked swizzle: 2928 = 8*366.
// ---------------------------------------------------------------------------
__global__ __launch_bounds__(256, 2) void proj_gemm(
    const float* __restrict__ Aq, const float* __restrict__ Ak, const float* __restrict__ Av,
    const unsigned short* __restrict__ Wt, const float* __restrict__ biasp,
    unsigned short* __restrict__ Yq, unsigned short* __restrict__ Yk, unsigned short* __restrict__ Yv)
{
    __shared__ __align__(16) unsigned short As[2][128*64];   // 16 KB each
    __shared__ __align__(16) unsigned short Bs[2][128*64];   // 16 KB each

    int orig = blockIdx.x;
    int wg = (orig & 7) * 366 + (orig >> 3);  // bijective XCD chunking (2928=8*366)
    int z = wg / 976; int rem = wg - z * 976;
    int mtile = rem >> 2; int ntile = rem & 3;

    const float* A = (z == 0) ? Aq : ((z == 1) ? Ak : Av);
    unsigned short* Y = (z == 0) ? Yq : ((z == 1) ? Yk : Yv);
    const unsigned short* Bt = Wt + z * 512 * 512 + ntile * 128 * 512;
    const float* bias = biasp + z * 512;

    int t = threadIdx.x;
    int wid = t >> 6, lane = t & 63;
    int wm = wid >> 1, wn = wid & 1;
    int lm = lane & 15, lg = lane >> 4;

    long mbase = (long)mtile * 128;

    // A staging: thread t loads rows rl = i*16 + (t>>4), fp32 cols (t&15)*4..+3.
    // Per-instruction coalesced (consecutive lanes -> consecutive 16B).
    int tr = t >> 4, tc = t & 15;
    long aoffg[8];
    int awr[8];
    #pragma unroll
    for (int i = 0; i < 8; ++i) {
        int rl = i * 16 + tr;
        long rg = mbase + rl; if (rg >= MROWS) rg = MROWS - 1;   // clamp (stores guarded)
        aoffg[i] = rg * 512 + tc * 4;
        // LDS 8B-unit index: row*16 + swizzled-granule*2 + half
        awr[i] = rl * 16 + (((tc >> 1) ^ (rl & 7)) << 1) + (tc & 1);
    }
    // B gload: 16B granules, inverse-swizzled global source, linear LDS dest
    int boff[4];
    #pragma unroll
    for (int r = 0; r < 4; ++r) {
        int G = ((r * 4 + wid) << 6) + lane;      // 0..1023
        int row = G >> 3;
        int slot = (G & 7) ^ (row & 7);
        boff[r] = row * 512 + slot * 8;
    }

    f32x4 areg[8];
    f32x4 acc[4][4] = {};

    // prologue: stage tile 0
    #pragma unroll
    for (int r = 0; r < 4; ++r)
        gload16(Bt + boff[r], &Bs[0][(r * 4 + wid) << 9]);
    #pragma unroll
    for (int i = 0; i < 8; ++i)
        areg[i] = *(const f32x4*)(A + aoffg[i]);
    {
        u32x2* dst = (u32x2*)&As[0][0];
        #pragma unroll
        for (int i = 0; i < 8; ++i) {
            u32x2 w;
            w[0] = cvt2(areg[i][0], areg[i][1]);
            w[1] = cvt2(areg[i][2], areg[i][3]);
            dst[awr[i]] = w;
        }
    }
    asm volatile("s_waitcnt vmcnt(0)" ::: "memory");
    __syncthreads();

    int buf = 0;
    for (int kk = 0; kk < 8; ++kk) {
        // issue next tile's loads BEFORE compute (latency hides under MFMA)
        if (kk < 7) {
            const int k0 = (kk + 1) * 64;
            #pragma unroll
            for (int r = 0; r < 4; ++r)
                gload16(Bt + boff[r] + k0, &Bs[buf ^ 1][(r * 4 + wid) << 9]);
            #pragma unroll
            for (int i = 0; i < 8; ++i)
                areg[i] = *(const f32x4*)(A + aoffg[i] + k0);
        }
        // compute current tile
        #pragma unroll
        for (int ks = 0; ks < 2; ++ks) {
            s16x8 afr[4], bfr[4];
            #pragma unroll
            for (int mf = 0; mf < 4; ++mf) {
                int row = wm * 64 + mf * 16 + lm;
                afr[mf] = ((const s16x8*)As[buf])[row * 8 + ((ks * 4 + lg) ^ (row & 7))];
            }
            #pragma unroll
            for (int nf = 0; nf < 4; ++nf) {
                int row = wn * 64 + nf * 16 + lm;
                bfr[nf] = ((const s16x8*)Bs[buf])[row * 8 + ((ks * 4 + lg) ^ (row & 7))];
            }
            #pragma unroll
            for (int mf = 0; mf < 4; ++mf)
                #pragma unroll
                for (int nf = 0; nf < 4; ++nf)
                    acc[mf][nf] = __builtin_amdgcn_mfma_f32_16x16x32_bf16(afr[mf], bfr[nf], acc[mf][nf], 0, 0, 0);
        }
        // convert + write next A tile (auto vmcnt waits on areg), drain B gloads
        if (kk < 7) {
            u32x2* dst = (u32x2*)&As[buf ^ 1][0];
            #pragma unroll
            for (int i = 0; i < 8; ++i) {
                u32x2 w;
                w[0] = cvt2(areg[i][0], areg[i][1]);
                w[1] = cvt2(areg[i][2], areg[i][3]);
                dst[awr[i]] = w;
            }
            asm volatile("s_waitcnt vmcnt(0)" ::: "memory");
        }
        __syncthreads();
        buf ^= 1;
    }

    // epilogue: + bias, cast bf16, store (C layout: col=lane&15, row=(lane>>4)*4+j)
    #pragma unroll
    for (int nf = 0; nf < 4; ++nf) {
        int gcol = ntile * 128 + wn * 64 + nf * 16 + lm;
        float bv = bias[gcol];
        #pragma unroll
        for (int mf = 0; mf < 4; ++mf) {
            #pragma unroll
            for (int j = 0; j < 4; ++j) {
                long grow = mbase + wm * 64 + mf * 16 + lg * 4 + j;
                if (grow < MROWS)
                    Y[grow * 512 + gcol] = f2bf(acc[mf][nf][j] + bv);
            }
        }
    }
}

// ---------------------------------------------------------------------------
// K2: attention (unchanged this round).
// ---------------------------------------------------------------------------
__global__ __launch_bounds__(256) void attn_kernel(
    const unsigned short* __restrict__ Qw, const unsigned short* __restrict__ Kw,
    const unsigned short* __restrict__ Vw, unsigned short* __restrict__ Ow)
{
    __shared__ unsigned short Qs[64*64];
    __shared__ unsigned short Ks[64*64];
    __shared__ unsigned short Vts[64*64];
    __shared__ unsigned short Ps[64*64];

    int qc = blockIdx.x;
    int h  = blockIdx.y;
    int bt = blockIdx.z;
    int t = threadIdx.x;
    int wid = t >> 6, lane = t & 63, lm = lane & 15, lg = lane >> 4;

    long rowbase = (long)bt * NN;
    int colbase = h * 64;
    int q0 = qc * 64;

    {
        int i = t >> 2, quarter = t & 3;
        const u32x4* src = (const u32x4*)(Qw + (rowbase + q0 + i) * 512 + colbase);
        u32x4* dst = (u32x4*)Qs;
        #pragma unroll
        for (int s = 0; s < 2; ++s) {
            int slot = quarter + s * 4;
            u32x4 v = 0;
            if (q0 + i < NN) v = src[slot];
            dst[i * 8 + (slot ^ (i & 7))] = v;
        }
    }
    __syncthreads();
    s16x8 aq[2];
    {
        int row = wid * 16 + lm;
        aq[0] = ((const s16x8*)Qs)[row * 8 + ((0 + lg) ^ (row & 7))];
        aq[1] = ((const s16x8*)Qs)[row * 8 + ((4 + lg) ^ (row & 7))];
    }

    f32x4 oacc[4] = {};
    float mrow[4], lrow[4];
    #pragma unroll
    for (int j = 0; j < 4; ++j) { mrow[j] = -__builtin_inff(); lrow[j] = 0.f; }

    for (int kv0 = 0; kv0 < NN; kv0 += 64) {
        __syncthreads();
        {
            int i = t >> 2, quarter = t & 3;
            const u32x4* src = (const u32x4*)(Kw + (rowbase + kv0 + i) * 512 + colbase);
            u32x4* dst = (u32x4*)Ks;
            #pragma unroll
            for (int s = 0; s < 2; ++s) {
                int slot = quarter + s * 4;
                u32x4 v = 0;
                if (kv0 + i < NN) v = src[slot];
                dst[i * 8 + (slot ^ (i & 7))] = v;
            }
        }
        {
            int i = t >> 2, quarter = t & 3;
            unsigned short vb[16] __attribute__((aligned(16)));
            if (kv0 + i < NN) {
                const u32x4* src = (const u32x4*)(Vw + (rowbase + kv0 + i) * 512 + colbase + quarter * 16);
                *((u32x4*)vb) = src[0];
                *((u32x4*)(vb + 8)) = src[1];
            } else {
                #pragma unroll
                for (int x = 0; x < 16; ++x) vb[x] = 0;
            }
            #pragma unroll
            for (int x = 0; x < 16; ++x) {
                int dk = quarter * 16 + x;
                Vts[dk * 64 + (i ^ ((dk & 7) << 3))] = vb[x];
            }
        }
        __syncthreads();

        f32x4 sacc[4] = {};
        #pragma unroll
        for (int ks = 0; ks < 2; ++ks) {
            #pragma unroll
            for (int nf = 0; nf < 4; ++nf) {
                int row = nf * 16 + lm;
                s16x8 bk = ((const s16x8*)Ks)[row * 8 + ((ks*4 + lg) ^ (row & 7))];
                sacc[nf] = __builtin_amdgcn_mfma_f32_16x16x32_bf16(aq[ks], bk, sacc[nf], 0, 0, 0);
            }
        }
        float p[4][4], tmax[4];
        #pragma unroll
        for (int j = 0; j < 4; ++j) tmax[j] = -__builtin_inff();
        #pragma unroll
        for (int nf = 0; nf < 4; ++nf) {
            int col = kv0 + nf * 16 + lm;
            bool valid = col < NN;
            #pragma unroll
            for (int j = 0; j < 4; ++j) {
                float s = valid ? sacc[nf][j] * 0.125f : -__builtin_inff();
                p[nf][j] = s;
                tmax[j] = fmaxf(tmax[j], s);
            }
        }
        #pragma unroll
        for (int j = 0; j < 4; ++j) {
            float v = tmax[j];
            v = fmaxf(v, __shfl_xor(v, 1, 16));
            v = fmaxf(v, __shfl_xor(v, 2, 16));
            v = fmaxf(v, __shfl_xor(v, 4, 16));
            v = fmaxf(v, __shfl_xor(v, 8, 16));
            tmax[j] = v;
        }
        float scl[4];
        #pragma unroll
        for (int j = 0; j < 4; ++j) {
            float mn = fmaxf(mrow[j], tmax[j]);
            float sc = __expf(mrow[j] - mn);
            float rs = 0.f;
            #pragma unroll
            for (int nf = 0; nf < 4; ++nf) {
                float pv = __expf(p[nf][j] - mn);
                p[nf][j] = pv;
                rs += pv;
            }
            rs += __shfl_xor(rs, 1, 16);
            rs += __shfl_xor(rs, 2, 16);
            rs += __shfl_xor(rs, 4, 16);
            rs += __shfl_xor(rs, 8, 16);
            lrow[j] = lrow[j] * sc + rs;
            mrow[j] = mn;
            scl[j] = sc;
        }
        #pragma unroll
        for (int df = 0; df < 4; ++df)
            #pragma unroll
            for (int j = 0; j < 4; ++j)
                oacc[df][j] *= scl[j];

        #pragma unroll
        for (int nf = 0; nf < 4; ++nf) {
            #pragma unroll
            for (int j = 0; j < 4; ++j) {
                int row = wid * 16 + lg * 4 + j;
                int col = nf * 16 + lm;
                Ps[row * 64 + (col ^ ((row & 7) << 3))] = f2bf(p[nf][j]);
            }
        }
        __syncthreads();

        #pragma unroll
        for (int ks = 0; ks < 2; ++ks) {
            int prow = wid * 16 + lm;
            s16x8 ap = ((const s16x8*)Ps)[prow * 8 + ((ks*4 + lg) ^ (prow & 7))];
            #pragma unroll
            for (int df = 0; df < 4; ++df) {
                int vrow = df * 16 + lm;
                s16x8 bv = ((const s16x8*)Vts)[vrow * 8 + ((ks*4 + lg) ^ (vrow & 7))];
                oacc[df] = __builtin_amdgcn_mfma_f32_16x16x32_bf16(ap, bv, oacc[df], 0, 0, 0);
            }
        }
    }

    #pragma unroll
    for (int df = 0; df < 4; ++df) {
        int dk = df * 16 + lm;
        #pragma unroll
        for (int j = 0; j < 4; ++j) {
            int rloc = q0 + wid * 16 + lg * 4 + j;
            if (rloc < NN) {
                float v = oacc[df][j] / lrow[j];
                Ow[(rowbase + rloc) * 512 + colbase + dk] = f2bf(v);
            }
        }
    }
}

// ---------------------------------------------------------------------------
// K3: out-projection + residual, double-buffered gload_lds pipeline.
// Writes bf16 pre-LN tensor. XCD chunking: 976 = 8*122. LDS 64KB, 2 blk/CU.
// ---------------------------------------------------------------------------
__global__ __launch_bounds__(256, 2) void out_gemm(
    const unsigned short* __restrict__ A, const unsigned short* __restrict__ Bt0,
    const float* __restrict__ X, unsigned short* __restrict__ Out)
{
    __shared__ __align__(16) unsigned short As[2][128*64];
    __shared__ __align__(16) unsigned short Bs[2][128*64];

    int orig = blockIdx.x;
    int wg = (orig & 7) * 122 + (orig >> 3);
    int mtile = wg >> 2; int ntile = wg & 3;

    const unsigned short* Bt = Bt0 + ntile * 128 * 512;

    int t = threadIdx.x;
    int wid = t >> 6, lane = t & 63;
    int wm = wid >> 1, wn = wid & 1;
    int lm = lane & 15, lg = lane >> 4;

    long mbase = (long)mtile * 128;
    const unsigned short* Abase = A + mbase * 512;

    int aoff[4], boff[4];
    #pragma unroll
    for (int r = 0; r < 4; ++r) {
        int G = ((r * 4 + wid) << 6) + lane;      // 0..1023
        int row = G >> 3;
        int slot = (G & 7) ^ (row & 7);
        int rowc = row;
        if (mbase + row > MROWS - 1) rowc = (int)(MROWS - 1 - mbase);
        aoff[r] = rowc * 512 + slot * 8;
        boff[r] = row * 512 + slot * 8;
    }

    f32x4 acc[4][4] = {};

    // prologue: stage tile 0
    #pragma unroll
    for (int r = 0; r < 4; ++r) {
        gload16(Abase + aoff[r], &As[0][(r * 4 + wid) << 9]);
        gload16(Bt + boff[r],    &Bs[0][(r * 4 + wid) << 9]);
    }
    asm volatile("s_waitcnt vmcnt(0)" ::: "memory");
    __syncthreads();

    int buf = 0;
    for (int kk = 0; kk < 8; ++kk) {
        if (kk < 7) {
            const int k0 = (kk + 1) * 64;
            #pragma unroll
            for (int r = 0; r < 4; ++r) {
                gload16(Abase + aoff[r] + k0, &As[buf ^ 1][(r * 4 + wid) << 9]);
                gload16(Bt + boff[r] + k0,    &Bs[buf ^ 1][(r * 4 + wid) << 9]);
            }
        }
        #pragma unroll
        for (int ks = 0; ks < 2; ++ks) {
            s16x8 afr[4], bfr[4];
            #pragma unroll
            for (int mf = 0; mf < 4; ++mf) {
                int row = wm * 64 + mf * 16 + lm;
                afr[mf] = ((const s16x8*)As[buf])[row * 8 + ((ks * 4 + lg) ^ (row & 7))];
            }
            #pragma unroll
            for (int nf = 0; nf < 4; ++nf) {
                int row = wn * 64 + nf * 16 + lm;
                bfr[nf] = ((const s16x8*)Bs[buf])[row * 8 + ((ks * 4 + lg) ^ (row & 7))];
            }
            #pragma unroll
            for (int mf = 0; mf < 4; ++mf)
                #pragma unroll
                for (int nf = 0; nf < 4; ++nf)
                    acc[mf][nf] = __builtin_amdgcn_mfma_f32_16x16x32_bf16(afr[mf], bfr[nf], acc[mf][nf], 0, 0, 0);
        }
        asm volatile("s_waitcnt vmcnt(0)" ::: "memory");
        __syncthreads();
        buf ^= 1;
    }

    #pragma unroll
    for (int nf = 0; nf < 4; ++nf) {
        int gcol = ntile * 128 + wn * 64 + nf * 16 + lm;
        #pragma unroll
        for (int mf = 0; mf < 4; ++mf) {
            #pragma unroll
            for (int j = 0; j < 4; ++j) {
                long grow = mbase + wm * 64 + mf * 16 + lg * 4 + j;
                if (grow < MROWS) {
                    float r = acc[mf][nf][j] + X[grow * 512 + gcol];
                    Out[grow * 512 + gcol] = f2bf(r);
                }
            }
        }
    }
}

// ---------------------------------------------------------------------------
// K4: LayerNorm over D=512 (bf16 input, fp32 output), one wave per row.
// ---------------------------------------------------------------------------
__global__ __launch_bounds__(256) void ln_kernel(
    const unsigned short* __restrict__ T, const float* __restrict__ gamma,
    const float* __restrict__ beta, float* __restrict__ Outp)
{
    int wid = threadIdx.x >> 6, lane = threadIdx.x & 63;
    long row = (long)blockIdx.x * 4 + wid;
    s16x8 h = ((const s16x8*)(T + row * 512))[lane];
    float v[8];
    #pragma unroll
    for (int j = 0; j < 8; ++j) {
        union { float f; unsigned int u; } x;
        x.u = ((unsigned int)(unsigned short)h[j]) << 16;
        v[j] = x.f;
    }
    float s = 0.f, sq = 0.f;
    #pragma unroll
    for (int j = 0; j < 8; ++j) { s += v[j]; sq += v[j] * v[j]; }
    #pragma unroll
    for (int m = 1; m < 64; m <<= 1) {
        s  += __shfl_xor(s, m);
        sq += __shfl_xor(sq, m);
    }
    float mean = s * (1.f / 512.f);
    float var = sq * (1.f / 512.f) - mean * mean;
    float rstd = rsqrtf(var + 1e-5f);
    const float4* g = (const float4*)gamma;
    const float4* b = (const float4*)beta;
    float4 g0 = g[lane * 2], g1 = g[lane * 2 + 1];
    float4 b0 = b[lane * 2], b1 = b[lane * 2 + 1];
    float4 o0, o1;
    o0.x = (v[0] - mean) * rstd * g0.x + b0.x;
    o0.y = (v[1] - mean) * rstd * g0.y + b0.y;
    o0.z = (v[2] - mean) * rstd * g0.z + b0.z;
    o0.w = (v[3] - mean) * rstd * g0.w + b0.w;
    o1.x = (v[4] - mean) * rstd * g1.x + b1.x;
    o1.y = (v[5] - mean) * rstd * g1.y + b1.y;
    o1.z = (v[6] - mean) * rstd * g1.z + b1.z;
    o1.w = (v[7] - mean) * rstd * g1.w + b1.w;
    float4* dst = (float4*)(Outp + row * 512);
    dst[lane * 2]     = o0;
    dst[lane * 2 + 1] = o1;
}

// ---------------------------------------------------------------------------
extern "C" void kernel_launch(void* const* d_in, const int* in_sizes, int n_in,
                              void* d_out, int out_size, void* d_ws, size_t ws_size,
                              hipStream_t stream)
{
    const float* X  = (const float*)d_in[0];
    const float* Q  = (const float*)d_in[1];
    const float* K  = (const float*)d_in[2];
    const float* V  = (const float*)d_in[3];
    const float* Wh = (const float*)d_in[4];
    const float* bi = (const float*)d_in[5];
    const float* Wo = (const float*)d_in[6];
    const float* gamma = (const float*)d_in[7];
    const float* beta  = (const float*)d_in[8];

    char* ws = (char*)d_ws;
    const size_t msz = (size_t)MROWS * 512 * 2;     // one bf16 matrix ~31.9 MB
    unsigned short* q_ws = (unsigned short*)(ws);
    unsigned short* k_ws = (unsigned short*)(ws + msz);
    unsigned short* v_ws = (unsigned short*)(ws + 2 * msz);
    unsigned short* o_ws = (unsigned short*)(ws + 3 * msz);
    unsigned short* WtH  = (unsigned short*)(ws + 4 * msz);
    unsigned short* WtO  = (unsigned short*)(ws + 4 * msz + (size_t)3*512*512*2);
    float* biasp         = (float*)(ws + 4 * msz + (size_t)4*512*512*2);
    unsigned short* tmpb = q_ws;   // pre-LN bf16 tensor; q dead after attention

    prep_kernel<<<4102, 256, 0, stream>>>(Wh, bi, Wo, WtH, WtO, biasp);

    proj_gemm<<<2928, 256, 0, stream>>>(Q, K, V, WtH, biasp, q_ws, k_ws, v_ws);

    dim3 g2(6, 8, 96);
    attn_kernel<<<g2, 256, 0, stream>>>(q_ws, k_ws, v_ws, o_ws);

    out_gemm<<<976, 256, 0, stream>>>(o_ws, WtO, X, tmpb);

    ln_kernel<<<7800, 256, 0, stream>>>(tmpb, gamma, beta, (float*)d_out);
}

// Round 5
// 400.637 us; speedup vs baseline: 1.0210x; 1.0210x over previous
//
#include <hip/hip_runtime.h>
#include <hip/hip_bf16.h>
#include <stdint.h>

// Problem constants
#define BB 4
#define TT 24
#define NN 325          // sequence length per (b,t)
#define DD 512
#define NH 8
#define DKH 64          // d_k per head
#define MROWS (BB*TT*NN)   // 31200 total rows
#define BTC (BB*TT)        // 96

typedef __attribute__((ext_vector_type(4))) float f32x4;
typedef __attribute__((ext_vector_type(8))) short s16x8;
typedef __attribute__((ext_vector_type(4))) unsigned int u32x4;

__device__ __forceinline__ unsigned short f2bf(float f) {
    union { float f; unsigned int u; } x; x.f = f;
    unsigned int u = x.u;
    u += 0x7fffu + ((u >> 16) & 1u);   // RNE
    return (unsigned short)(u >> 16);
}
// packed f32->bf16 (RNE) via HW instruction
__device__ __forceinline__ unsigned int cvt2(float a, float b) {
    unsigned int r;
    asm("v_cvt_pk_bf16_f32 %0, %1, %2" : "=v"(r) : "v"(a), "v"(b));
    return r;
}

__device__ __forceinline__ void gload16(const void* g, void* l) {
    __builtin_amdgcn_global_load_lds((const __attribute__((address_space(1))) void*)g,
                                     (__attribute__((address_space(3))) void*)l, 16, 0, 0);
}

// ---------------------------------------------------------------------------
// K0: weight prep. Permute head-interleaved columns (d = dk*8+h  ->  h*64+dk),
// transpose to [n][k] layout, convert to bf16.
// ---------------------------------------------------------------------------
__global__ void prep_kernel(const float* __restrict__ Wh, const float* __restrict__ bias,
                            const float* __restrict__ Wo,
                            unsigned short* __restrict__ WtH, unsigned short* __restrict__ WtO,
                            float* __restrict__ biasp)
{
    int idx = blockIdx.x * 256 + threadIdx.x;
    if (idx < 3*512*512) {
        int i = idx >> 18; int rem = idx & 262143;
        int cp = rem >> 9; int e = rem & 511;
        int c = ((cp & 63) << 3) | (cp >> 6);
        WtH[idx] = f2bf(Wh[(i << 18) + (e << 9) + c]);
        return;
    }
    int idx2 = idx - 3*512*512;
    if (idx2 >= 0 && idx2 < 512*512) {
        int c = idx2 >> 9; int ep = idx2 & 511;
        int row = ((ep & 63) << 3) | (ep >> 6);
        WtO[idx2] = f2bf(Wo[(row << 9) + c]);
        return;
    }
    int idx3 = idx2 - 512*512;
    if (idx3 >= 0 && idx3 < 3*512) {
        int i = idx3 >> 9; int cp = idx3 & 511;
        int c = ((cp & 63) << 3) | (cp >> 6);
        biasp[idx3] = bias[(i << 9) + c];
    }
}

// ---------------------------------------------------------------------------
// K0b: fp32 -> bf16 convert (one full input matrix, 15.97M elems).
// 7800 blocks x 256 thr x 8 elems, fully coalesced 16B/thread each way.
// ---------------------------------------------------------------------------
__global__ __launch_bounds__(256) void cvt_kernel(const float* __restrict__ src,
                                                  unsigned short* __restrict__ dst)
{
    long i = ((long)blockIdx.x * 256 + threadIdx.x) * 8;
    f32x4 a = *(const f32x4*)(src + i);
    f32x4 b = *(const f32x4*)(src + i + 4);
    u32x4 o;
    o[0] = cvt2(a[0], a[1]);
    o[1] = cvt2(a[2], a[3]);
    o[2] = cvt2(b[0], b[1]);
    o[3] = cvt2(b[2], b[3]);
    *(u32x4*)(dst + i) = o;
}

// ---------------------------------------------------------------------------
// K1: projection GEMM (one z per launch), m97-clone: bf16 A and B both via
// global_load_lds (pre-swizzled source, linear LDS dest, XOR-swizzled read).
// BM=128 BN=128 BK=64, 4 waves (2x2), single 32KB LDS buffer, 2-phase loop.
// 4-5 blocks/CU. XCD-chunked swizzle: 976 = 8*122.
// ---------------------------------------------------------------------------
__global__ __launch_bounds__(256) void proj_gemm(
    const unsigned short* __restrict__ A, const unsigned short* __restrict__ Bt0,
    const float* __restrict__ bias, unsigned short* __restrict__ Y)
{
    __shared__ __align__(16) unsigned short As[128*64];
    __shared__ __align__(16) unsigned short Bs[128*64];

    int orig = blockIdx.x;
    int wg = (orig & 7) * 122 + (orig >> 3);   // bijective (976 = 8*122)
    int mtile = wg >> 2; int ntile = wg & 3;

    const unsigned short* Bt = Bt0 + ntile * 128 * 512;

    int t = threadIdx.x;
    int wid = t >> 6, lane = t & 63;
    int wm = wid >> 1, wn = wid & 1;
    int lm = lane & 15, lg = lane >> 4;

    long mbase = (long)mtile * 128;
    const unsigned short* Abase = A + mbase * 512;

    // 16B-granule staging offsets: LDS linear pos G holds global granule
    // (row = G>>3, slot = (G&7) ^ (row&7)); read-side XOR undoes it.
    int aoff[4], boff[4];
    #pragma unroll
    for (int r = 0; r < 4; ++r) {
        int G = ((r * 4 + wid) << 6) + lane;      // 0..1023
        int row = G >> 3;
        int slot = (G & 7) ^ (row & 7);
        int rowc = row;
        if (mbase + row > MROWS - 1) rowc = (int)(MROWS - 1 - mbase);  // clamp tail
        aoff[r] = rowc * 512 + slot * 8;
        boff[r] = row * 512 + slot * 8;
    }

    f32x4 acc[4][4] = {};

    for (int kk = 0; kk < 8; ++kk) {
        const int k0 = kk * 64;
        __syncthreads();                          // prev compute done reading LDS
        #pragma unroll
        for (int r = 0; r < 4; ++r) {
            gload16(Abase + aoff[r] + k0, &As[(r * 4 + wid) << 9]);
            gload16(Bt + boff[r] + k0,    &Bs[(r * 4 + wid) << 9]);
        }
        asm volatile("s_waitcnt vmcnt(0)" ::: "memory");
        __syncthreads();

        #pragma unroll
        for (int ks = 0; ks < 2; ++ks) {
            s16x8 afr[4], bfr[4];
            #pragma unroll
            for (int mf = 0; mf < 4; ++mf) {
                int row = wm * 64 + mf * 16 + lm;
                afr[mf] = ((const s16x8*)As)[row * 8 + ((ks * 4 + lg) ^ (row & 7))];
            }
            #pragma unroll
            for (int nf = 0; nf < 4; ++nf) {
                int row = wn * 64 + nf * 16 + lm;
                bfr[nf] = ((const s16x8*)Bs)[row * 8 + ((ks * 4 + lg) ^ (row & 7))];
            }
            #pragma unroll
            for (int mf = 0; mf < 4; ++mf)
                #pragma unroll
                for (int nf = 0; nf < 4; ++nf)
                    acc[mf][nf] = __builtin_amdgcn_mfma_f32_16x16x32_bf16(afr[mf], bfr[nf], acc[mf][nf], 0, 0, 0);
        }
    }

    // epilogue: + bias, cast bf16, store (C layout: col=lane&15, row=(lane>>4)*4+j)
    #pragma unroll
    for (int nf = 0; nf < 4; ++nf) {
        int gcol = ntile * 128 + wn * 64 + nf * 16 + lm;
        float bv = bias[gcol];
        #pragma unroll
        for (int mf = 0; mf < 4; ++mf) {
            #pragma unroll
            for (int j = 0; j < 4; ++j) {
                long grow = mbase + wm * 64 + mf * 16 + lg * 4 + j;
                if (grow < MROWS)
                    Y[grow * 512 + gcol] = f2bf(acc[mf][nf][j] + bv);
            }
        }
    }
}

// ---------------------------------------------------------------------------
// K2: attention. 1D grid with XCD-co-locating swizzle: the 6 qc-blocks of one
// (bt,h) share an XCD so K/V panels are L2-resident after the first read.
// ---------------------------------------------------------------------------
__global__ __launch_bounds__(256) void attn_kernel(
    const unsigned short* __restrict__ Qw, const unsigned short* __restrict__ Kw,
    const unsigned short* __restrict__ Vw, unsigned short* __restrict__ Ow)
{
    __shared__ unsigned short Qs[64*64];
    __shared__ unsigned short Ks[64*64];
    __shared__ unsigned short Vts[64*64];
    __shared__ unsigned short Ps[64*64];

    int bid = blockIdx.x;          // 0..4607
    int x = bid & 7, s = bid >> 3; // x = XCD slot, s in [0,576)
    int qc = s % 6;
    int gi = s / 6;                // 0..95
    int g  = x + 8 * gi;           // group 0..767
    int h  = g & 7, bt = g >> 3;

    int t = threadIdx.x;
    int wid = t >> 6, lane = t & 63, lm = lane & 15, lg = lane >> 4;

    long rowbase = (long)bt * NN;
    int colbase = h * 64;
    int q0 = qc * 64;

    {
        int i = t >> 2, quarter = t & 3;
        const u32x4* src = (const u32x4*)(Qw + (rowbase + q0 + i) * 512 + colbase);
        u32x4* dst = (u32x4*)Qs;
        #pragma unroll
        for (int ss = 0; ss < 2; ++ss) {
            int slot = quarter + ss * 4;
            u32x4 v = 0;
            if (q0 + i < NN) v = src[slot];
            dst[i * 8 + (slot ^ (i & 7))] = v;
        }
    }
    __syncthreads();
    s16x8 aq[2];
    {
        int row = wid * 16 + lm;
        aq[0] = ((const s16x8*)Qs)[row * 8 + ((0 + lg) ^ (row & 7))];
        aq[1] = ((const s16x8*)Qs)[row * 8 + ((4 + lg) ^ (row & 7))];
    }

    f32x4 oacc[4] = {};
    float mrow[4], lrow[4];
    #pragma unroll
    for (int j = 0; j < 4; ++j) { mrow[j] = -__builtin_inff(); lrow[j] = 0.f; }

    for (int kv0 = 0; kv0 < NN; kv0 += 64) {
        __syncthreads();
        {
            int i = t >> 2, quarter = t & 3;
            const u32x4* src = (const u32x4*)(Kw + (rowbase + kv0 + i) * 512 + colbase);
            u32x4* dst = (u32x4*)Ks;
            #pragma unroll
            for (int ss = 0; ss < 2; ++ss) {
                int slot = quarter + ss * 4;
                u32x4 v = 0;
                if (kv0 + i < NN) v = src[slot];
                dst[i * 8 + (slot ^ (i & 7))] = v;
            }
        }
        {
            int i = t >> 2, quarter = t & 3;
            unsigned short vb[16] __attribute__((aligned(16)));
            if (kv0 + i < NN) {
                const u32x4* src = (const u32x4*)(Vw + (rowbase + kv0 + i) * 512 + colbase + quarter * 16);
                *((u32x4*)vb) = src[0];
                *((u32x4*)(vb + 8)) = src[1];
            } else {
                #pragma unroll
                for (int xx = 0; xx < 16; ++xx) vb[xx] = 0;
            }
            #pragma unroll
            for (int xx = 0; xx < 16; ++xx) {
                int dk = quarter * 16 + xx;
                Vts[dk * 64 + (i ^ ((dk & 7) << 3))] = vb[xx];
            }
        }
        __syncthreads();

        f32x4 sacc[4] = {};
        #pragma unroll
        for (int ks = 0; ks < 2; ++ks) {
            #pragma unroll
            for (int nf = 0; nf < 4; ++nf) {
                int row = nf * 16 + lm;
                s16x8 bk = ((const s16x8*)Ks)[row * 8 + ((ks*4 + lg) ^ (row & 7))];
                sacc[nf] = __builtin_amdgcn_mfma_f32_16x16x32_bf16(aq[ks], bk, sacc[nf], 0, 0, 0);
            }
        }
        float p[4][4], tmax[4];
        #pragma unroll
        for (int j = 0; j < 4; ++j) tmax[j] = -__builtin_inff();
        #pragma unroll
        for (int nf = 0; nf < 4; ++nf) {
            int col = kv0 + nf * 16 + lm;
            bool valid = col < NN;
            #pragma unroll
            for (int j = 0; j < 4; ++j) {
                float sv = valid ? sacc[nf][j] * 0.125f : -__builtin_inff();
                p[nf][j] = sv;
                tmax[j] = fmaxf(tmax[j], sv);
            }
        }
        #pragma unroll
        for (int j = 0; j < 4; ++j) {
            float v = tmax[j];
            v = fmaxf(v, __shfl_xor(v, 1, 16));
            v = fmaxf(v, __shfl_xor(v, 2, 16));
            v = fmaxf(v, __shfl_xor(v, 4, 16));
            v = fmaxf(v, __shfl_xor(v, 8, 16));
            tmax[j] = v;
        }
        float scl[4];
        #pragma unroll
        for (int j = 0; j < 4; ++j) {
            float mn = fmaxf(mrow[j], tmax[j]);
            float sc = __expf(mrow[j] - mn);
            float rs = 0.f;
            #pragma unroll
            for (int nf = 0; nf < 4; ++nf) {
                float pv = __expf(p[nf][j] - mn);
                p[nf][j] = pv;
                rs += pv;
            }
            rs += __shfl_xor(rs, 1, 16);
            rs += __shfl_xor(rs, 2, 16);
            rs += __shfl_xor(rs, 4, 16);
            rs += __shfl_xor(rs, 8, 16);
            lrow[j] = lrow[j] * sc + rs;
            mrow[j] = mn;
            scl[j] = sc;
        }
        #pragma unroll
        for (int df = 0; df < 4; ++df)
            #pragma unroll
            for (int j = 0; j < 4; ++j)
                oacc[df][j] *= scl[j];

        #pragma unroll
        for (int nf = 0; nf < 4; ++nf) {
            #pragma unroll
            for (int j = 0; j < 4; ++j) {
                int row = wid * 16 + lg * 4 + j;
                int col = nf * 16 + lm;
                Ps[row * 64 + (col ^ ((row & 7) << 3))] = f2bf(p[nf][j]);
            }
        }
        __syncthreads();

        #pragma unroll
        for (int ks = 0; ks < 2; ++ks) {
            int prow = wid * 16 + lm;
            s16x8 ap = ((const s16x8*)Ps)[prow * 8 + ((ks*4 + lg) ^ (prow & 7))];
            #pragma unroll
            for (int df = 0; df < 4; ++df) {
                int vrow = df * 16 + lm;
                s16x8 bv = ((const s16x8*)Vts)[vrow * 8 + ((ks*4 + lg) ^ (vrow & 7))];
                oacc[df] = __builtin_amdgcn_mfma_f32_16x16x32_bf16(ap, bv, oacc[df], 0, 0, 0);
            }
        }
    }

    #pragma unroll
    for (int df = 0; df < 4; ++df) {
        int dk = df * 16 + lm;
        #pragma unroll
        for (int j = 0; j < 4; ++j) {
            int rloc = q0 + wid * 16 + lg * 4 + j;
            if (rloc < NN) {
                float v = oacc[df][j] / lrow[j];
                Ow[(rowbase + rloc) * 512 + colbase + dk] = f2bf(v);
            }
        }
    }
}

// ---------------------------------------------------------------------------
// K3: out-projection + residual, same m97-clone single-buffer structure.
// Writes bf16 pre-LN tensor. XCD chunking: 976 = 8*122.
// ---------------------------------------------------------------------------
__global__ __launch_bounds__(256) void out_gemm(
    const unsigned short* __restrict__ A, const unsigned short* __restrict__ Bt0,
    const float* __restrict__ X, unsigned short* __restrict__ Out)
{
    __shared__ __align__(16) unsigned short As[128*64];
    __shared__ __align__(16) unsigned short Bs[128*64];

    int orig = blockIdx.x;
    int wg = (orig & 7) * 122 + (orig >> 3);
    int mtile = wg >> 2; int ntile = wg & 3;

    const unsigned short* Bt = Bt0 + ntile * 128 * 512;

    int t = threadIdx.x;
    int wid = t >> 6, lane = t & 63;
    int wm = wid >> 1, wn = wid & 1;
    int lm = lane & 15, lg = lane >> 4;

    long mbase = (long)mtile * 128;
    const unsigned short* Abase = A + mbase * 512;

    int aoff[4], boff[4];
    #pragma unroll
    for (int r = 0; r < 4; ++r) {
        int G = ((r * 4 + wid) << 6) + lane;
        int row = G >> 3;
        int slot = (G & 7) ^ (row & 7);
        int rowc = row;
        if (mbase + row > MROWS - 1) rowc = (int)(MROWS - 1 - mbase);
        aoff[r] = rowc * 512 + slot * 8;
        boff[r] = row * 512 + slot * 8;
    }

    f32x4 acc[4][4] = {};

    for (int kk = 0; kk < 8; ++kk) {
        const int k0 = kk * 64;
        __syncthreads();
        #pragma unroll
        for (int r = 0; r < 4; ++r) {
            gload16(Abase + aoff[r] + k0, &As[(r * 4 + wid) << 9]);
            gload16(Bt + boff[r] + k0,    &Bs[(r * 4 + wid) << 9]);
        }
        asm volatile("s_waitcnt vmcnt(0)" ::: "memory");
        __syncthreads();

        #pragma unroll
        for (int ks = 0; ks < 2; ++ks) {
            s16x8 afr[4], bfr[4];
            #pragma unroll
            for (int mf = 0; mf < 4; ++mf) {
                int row = wm * 64 + mf * 16 + lm;
                afr[mf] = ((const s16x8*)As)[row * 8 + ((ks * 4 + lg) ^ (row & 7))];
            }
            #pragma unroll
            for (int nf = 0; nf < 4; ++nf) {
                int row = wn * 64 + nf * 16 + lm;
                bfr[nf] = ((const s16x8*)Bs)[row * 8 + ((ks * 4 + lg) ^ (row & 7))];
            }
            #pragma unroll
            for (int mf = 0; mf < 4; ++mf)
                #pragma unroll
                for (int nf = 0; nf < 4; ++nf)
                    acc[mf][nf] = __builtin_amdgcn_mfma_f32_16x16x32_bf16(afr[mf], bfr[nf], acc[mf][nf], 0, 0, 0);
        }
    }

    #pragma unroll
    for (int nf = 0; nf < 4; ++nf) {
        int gcol = ntile * 128 + wn * 64 + nf * 16 + lm;
        #pragma unroll
        for (int mf = 0; mf < 4; ++mf) {
            #pragma unroll
            for (int j = 0; j < 4; ++j) {
                long grow = mbase + wm * 64 + mf * 16 + lg * 4 + j;
                if (grow < MROWS) {
                    float r = acc[mf][nf][j] + X[grow * 512 + gcol];
                    Out[grow * 512 + gcol] = f2bf(r);
                }
            }
        }
    }
}

// ---------------------------------------------------------------------------
// K4: LayerNorm over D=512 (bf16 input, fp32 output), one wave per row.
// ---------------------------------------------------------------------------
__global__ __launch_bounds__(256) void ln_kernel(
    const unsigned short* __restrict__ T, const float* __restrict__ gamma,
    const float* __restrict__ beta, float* __restrict__ Outp)
{
    int wid = threadIdx.x >> 6, lane = threadIdx.x & 63;
    long row = (long)blockIdx.x * 4 + wid;
    s16x8 h = ((const s16x8*)(T + row * 512))[lane];
    float v[8];
    #pragma unroll
    for (int j = 0; j < 8; ++j) {
        union { float f; unsigned int u; } x;
        x.u = ((unsigned int)(unsigned short)h[j]) << 16;
        v[j] = x.f;
    }
    float s = 0.f, sq = 0.f;
    #pragma unroll
    for (int j = 0; j < 8; ++j) { s += v[j]; sq += v[j] * v[j]; }
    #pragma unroll
    for (int m = 1; m < 64; m <<= 1) {
        s  += __shfl_xor(s, m);
        sq += __shfl_xor(sq, m);
    }
    float mean = s * (1.f / 512.f);
    float var = sq * (1.f / 512.f) - mean * mean;
    float rstd = rsqrtf(var + 1e-5f);
    const float4* g = (const float4*)gamma;
    const float4* b = (const float4*)beta;
    float4 g0 = g[lane * 2], g1 = g[lane * 2 + 1];
    float4 b0 = b[lane * 2], b1 = b[lane * 2 + 1];
    float4 o0, o1;
    o0.x = (v[0] - mean) * rstd * g0.x + b0.x;
    o0.y = (v[1] - mean) * rstd * g0.y + b0.y;
    o0.z = (v[2] - mean) * rstd * g0.z + b0.z;
    o0.w = (v[3] - mean) * rstd * g0.w + b0.w;
    o1.x = (v[4] - mean) * rstd * g1.x + b1.x;
    o1.y = (v[5] - mean) * rstd * g1.y + b1.y;
    o1.z = (v[6] - mean) * rstd * g1.z + b1.z;
    o1.w = (v[7] - mean) * rstd * g1.w + b1.w;
    float4* dst = (float4*)(Outp + row * 512);
    dst[lane * 2]     = o0;
    dst[lane * 2 + 1] = o1;
}

// ---------------------------------------------------------------------------
extern "C" void kernel_launch(void* const* d_in, const int* in_sizes, int n_in,
                              void* d_out, int out_size, void* d_ws, size_t ws_size,
                              hipStream_t stream)
{
    const float* X  = (const float*)d_in[0];
    const float* Q  = (const float*)d_in[1];
    const float* K  = (const float*)d_in[2];
    const float* V  = (const float*)d_in[3];
    const float* Wh = (const float*)d_in[4];
    const float* bi = (const float*)d_in[5];
    const float* Wo = (const float*)d_in[6];
    const float* gamma = (const float*)d_in[7];
    const float* beta  = (const float*)d_in[8];

    char* ws = (char*)d_ws;
    const size_t msz = (size_t)MROWS * 512 * 2;     // one bf16 matrix ~31.9 MB
    unsigned short* q_ws = (unsigned short*)(ws);
    unsigned short* k_ws = (unsigned short*)(ws + msz);
    unsigned short* v_ws = (unsigned short*)(ws + 2 * msz);
    unsigned short* o_ws = (unsigned short*)(ws + 3 * msz);  // cvt buffer, later attn out
    unsigned short* WtH  = (unsigned short*)(ws + 4 * msz);
    unsigned short* WtO  = (unsigned short*)(ws + 4 * msz + (size_t)3*512*512*2);
    float* biasp         = (float*)(ws + 4 * msz + (size_t)4*512*512*2);
    unsigned short* tmpb = q_ws;   // pre-LN bf16 tensor; q dead after attention

    prep_kernel<<<4102, 256, 0, stream>>>(Wh, bi, Wo, WtH, WtO, biasp);

    // per-z: convert input to bf16 (into o_ws, dead until attention), then GEMM
    cvt_kernel<<<7800, 256, 0, stream>>>(Q, o_ws);
    proj_gemm<<<976, 256, 0, stream>>>(o_ws, WtH + 0 * 512 * 512, biasp + 0 * 512, q_ws);
    cvt_kernel<<<7800, 256, 0, stream>>>(K, o_ws);
    proj_gemm<<<976, 256, 0, stream>>>(o_ws, WtH + 1 * 512 * 512, biasp + 1 * 512, k_ws);
    cvt_kernel<<<7800, 256, 0, stream>>>(V, o_ws);
    proj_gemm<<<976, 256, 0, stream>>>(o_ws, WtH + 2 * 512 * 512, biasp + 2 * 512, v_ws);

    attn_kernel<<<4608, 256, 0, stream>>>(q_ws, k_ws, v_ws, o_ws);

    out_gemm<<<976, 256, 0, stream>>>(o_ws, WtO, X, tmpb);

    ln_kernel<<<7800, 256, 0, stream>>>(tmpb, gamma, beta, (float*)d_out);
}